// Round 18
// baseline (95.495 us; speedup 1.0000x reference)
//
#include <hip/hip_runtime.h>

#define KE_KCAL 332.0637f

constexpr int N_ATOMS = 6144;
constexpr int NREAL = 1200;             // triangular 256x64 tiles
constexpr int NPRED = 384;              // pred blocks (16 atoms each)
constexpr int PAD = 32;                 // 128 B line stride

typedef float v2f __attribute__((ext_vector_type(2)));
typedef float v4f __attribute__((ext_vector_type(4)));

// ---------------- kernel A: pred + per-block sums + pack + zero ctrs --------
__global__ __launch_bounds__(256) void pred_kernel(
    const float* __restrict__ f, const int* __restrict__ z,
    const float* __restrict__ w, const float* __restrict__ ztab,
    const float* __restrict__ xyz,
    float* __restrict__ qpart, float4* __restrict__ xqp,
    unsigned int* __restrict__ ctr1, unsigned int* __restrict__ ctr2)
{
    int t = threadIdx.x, b = blockIdx.x;
    int lane = t & 63, wid = t >> 6;

    if (b == 0) {                        // zero tree counters for pair
        if (t < 64) ctr1[t * PAD] = 0u;
        if (t == 64) *ctr2 = 0u;
    }

    int base = b * 16 + wid * 4;
    const float2* f2 = (const float2*)f;
    float2 wv = ((const float2*)w)[lane];
    float2 v0 = f2[(size_t)(base + 0) * 64 + lane];
    float2 v1 = f2[(size_t)(base + 1) * 64 + lane];
    float2 v2 = f2[(size_t)(base + 2) * 64 + lane];
    float2 v3 = f2[(size_t)(base + 3) * 64 + lane];
    float p0 = fmaf(v0.x, wv.x, v0.y * wv.y);
    float p1 = fmaf(v1.x, wv.x, v1.y * wv.y);
    float p2 = fmaf(v2.x, wv.x, v2.y * wv.y);
    float p3 = fmaf(v3.x, wv.x, v3.y * wv.y);
    #pragma unroll
    for (int off = 32; off > 0; off >>= 1) {
        p0 += __shfl_xor(p0, off, 64);
        p1 += __shfl_xor(p1, off, 64);
        p2 += __shfl_xor(p2, off, 64);
        p3 += __shfl_xor(p3, off, 64);
    }
    float ws_sum = 0.f;
    if (lane < 4) {
        int atom = base + lane;
        float pk = p0;
        pk = (lane == 1) ? p1 : pk;
        pk = (lane == 2) ? p2 : pk;
        pk = (lane == 3) ? p3 : pk;
        pk += ztab[z[atom]];
        xqp[atom] = make_float4(xyz[3*atom], xyz[3*atom+1], xyz[3*atom+2], pk);
        ws_sum = pk;
    }
    ws_sum += __shfl_xor(ws_sum, 1, 64);
    ws_sum += __shfl_xor(ws_sum, 2, 64);

    __shared__ float lred[4];
    if (lane == 0) lred[wid] = ws_sum;
    __syncthreads();
    if (t == 0) qpart[b] = lred[0] + lred[1] + lred[2] + lred[3];
}

// ---------------- packed pair term: 2 pairs per VOP3P stream ----------------
// term = rsq(x + fs(x)), x = r^2 (R15/R16-proven, absmax 3.8e-6).
// fs = h(v(u)): u = clamp((x-31.25)/50, +-1/2); cubic v; odd deg-7 h.
// Saturation outside [2.5, 7.5] A exact.
template<bool DIAG>
__device__ __forceinline__ v2f pair2(v2f jx, v2f jy, v2f jz, v2f jq,
                                     float px, float py, float pz, float qi,
                                     int k0, int jthresh)
{
    v2f dx = px - jx, dy = py - jy, dz = pz - jz;
    v2f x  = __builtin_elementwise_fma(dx, dx,
             __builtin_elementwise_fma(dy, dy, dz * dz));
    v2f qq = qi * jq;
    if (DIAG) {
        qq.x = ((k0     > jthresh) && (x.x > 0.f)) ? qq.x : 0.f;
        qq.y = ((k0 + 1 > jthresh) && (x.y > 0.f)) ? qq.y : 0.f;
    }
    v2f u = __builtin_elementwise_fma(x, (v2f)(0.02f), (v2f)(-0.625f));
    u = __builtin_elementwise_min(__builtin_elementwise_max(u, (v2f)(-0.5f)),
                                  (v2f)(0.5f));
    v2f v = __builtin_elementwise_fma(u,
              __builtin_elementwise_fma(u,
                __builtin_elementwise_fma(u, (v2f)(0.333856f),
                                          (v2f)(-0.472136f)),
                (v2f)(0.916536f)),
              (v2f)(0.118034f));
    v2f v2 = v * v;
    v2f p  = __builtin_elementwise_fma(v2,
               __builtin_elementwise_fma(v2,
                 __builtin_elementwise_fma(v2, (v2f)(-8.f), (v2f)(12.f)),
                 (v2f)(-6.5f)),
               (v2f)(2.f));
    v2f arg = __builtin_elementwise_fma(-v, p, x + 0.5f);   // x + fs
    v2f rs;
    rs.x = __builtin_amdgcn_rsqf(arg.x);
    rs.y = __builtin_amdgcn_rsqf(arg.y);
    return qq * rs;
}

// ---------------- kernel B: pair energy + last-block finalize ---------------
// 1200 triangular blocks x 256 thr (R16 proven loop). Plain eblk[b] store
// (d_ws), release fetch_add on a padded tree counter (48x19 + 16x18 = 1200),
// the unique last block reduces eblk via agent-scope relaxed loads -> out0.
__global__ __launch_bounds__(256) void pair_kernel(
    const float4* __restrict__ xqp, const float* __restrict__ qpart,
    const float* __restrict__ total_charge,
    float* __restrict__ qout, float* __restrict__ eblk,
    unsigned int* __restrict__ ctr1, unsigned int* __restrict__ ctr2,
    float* __restrict__ out0)
{
    int t = threadIdx.x, b = blockIdx.x;
    int lane = t & 63, wid = t >> 6;
    __shared__ float lred[4];
    __shared__ int lfin;
    __shared__ __align__(16) float sx[64], sy[64], sz[64], sq[64];

    // charge correction from the 384 per-block partials
    float s = qpart[t];
    if (t < NPRED - 256) s += qpart[256 + t];
    #pragma unroll
    for (int off = 32; off > 0; off >>= 1)
        s += __shfl_xor(s, off, 64);
    if (lane == 0) lred[wid] = s;
    __syncthreads();
    float S = lred[0] + lred[1] + lred[2] + lred[3];
    float corr = (total_charge[0] - S) * (1.0f / (float)N_ATOMS);

    // decode triangular (bi, bj): bj in [4*bi, 96)
    int bi = 0, off = 0;
    while (b >= off + (96 - 4 * bi)) { off += 96 - 4 * bi; ++bi; }
    int bj = 4 * bi + (b - off);

    int gj0 = bj * 64;
    if (t < 64) {
        float4 a = xqp[gj0 + t];
        sx[t] = a.x; sy[t] = a.y; sz[t] = a.z; sq[t] = a.w + corr;
    }
    int gi = bi * 256 + t;
    float4 pi = xqp[gi];
    float qi = pi.w + corr;
    if (bj == 4 * bi) qout[gi] = qi;
    __syncthreads();

    int jthresh = gi - gj0;             // pair valid iff k > jthresh
    bool diag = (bj - 4 * bi) < 4;      // i/j ranges overlap (wave-uniform)

    v2f accA = {0.f, 0.f}, accB = {0.f, 0.f};

#define PAIR_LOOP(DIAG_FLAG)                                                  \
    {                                                                         \
        v4f cx = *(const v4f*)&sx[0], cy = *(const v4f*)&sy[0];               \
        v4f cz = *(const v4f*)&sz[0], cq = *(const v4f*)&sq[0];               \
        _Pragma("unroll")                                                     \
        for (int k = 0; k < 64; k += 4) {                                     \
            v4f nx, ny, nz, nq;                                               \
            if (k + 4 < 64) {                                                 \
                nx = *(const v4f*)&sx[k+4]; ny = *(const v4f*)&sy[k+4];       \
                nz = *(const v4f*)&sz[k+4]; nq = *(const v4f*)&sq[k+4];       \
            }                                                                 \
            accA += pair2<DIAG_FLAG>(cx.lo, cy.lo, cz.lo, cq.lo,              \
                                     pi.x, pi.y, pi.z, qi, k,     jthresh);   \
            accB += pair2<DIAG_FLAG>(cx.hi, cy.hi, cz.hi, cq.hi,              \
                                     pi.x, pi.y, pi.z, qi, k + 2, jthresh);   \
            cx = nx; cy = ny; cz = nz; cq = nq;                               \
        }                                                                     \
    }

    if (diag) PAIR_LOOP(true) else PAIR_LOOP(false)
#undef PAIR_LOOP

    float acc = (accA.x + accA.y) + (accB.x + accB.y);

    #pragma unroll
    for (int o2 = 32; o2 > 0; o2 >>= 1)
        acc += __shfl_down(acc, o2, 64);
    __syncthreads();                    // lred reuse
    if (lane == 0) lred[wid] = acc;
    __syncthreads();
    if (t == 0) {
        eblk[b] = lred[0] + lred[1] + lred[2] + lred[3];
        // release orders the eblk store to device scope before the bump
        int g = b & 63;
        unsigned int gcnt = (g < 48) ? 19u : 18u;   // 48*19 + 16*18 = 1200
        int fin = 0;
        unsigned int o1 = __hip_atomic_fetch_add(&ctr1[g * PAD], 1u,
            __ATOMIC_ACQ_REL, __HIP_MEMORY_SCOPE_AGENT);
        if (o1 == gcnt - 1u) {
            unsigned int o2c = __hip_atomic_fetch_add(ctr2, 1u,
                __ATOMIC_ACQ_REL, __HIP_MEMORY_SCOPE_AGENT);
            fin = (o2c == 63u);
        }
        lfin = fin;
    }
    __syncthreads();

    if (lfin) {                         // unique last block: reduce -> out0
        float e = 0.f;
        for (int k = t; k < NREAL; k += 256)
            e += __hip_atomic_load(&eblk[k], __ATOMIC_RELAXED,
                                   __HIP_MEMORY_SCOPE_AGENT);
        #pragma unroll
        for (int o2 = 32; o2 > 0; o2 >>= 1)
            e += __shfl_down(e, o2, 64);
        if (lane == 0) lred[wid] = e;
        __syncthreads();
        if (t == 0) out0[0] = KE_KCAL * (lred[0] + lred[1] + lred[2] + lred[3]);
    }
}

extern "C" void kernel_launch(void* const* d_in, const int* in_sizes, int n_in,
                              void* d_out, int out_size, void* d_ws, size_t ws_size,
                              hipStream_t stream) {
    const float* f    = (const float*)d_in[0];
    const int*   z    = (const int*)  d_in[1];
    const float* xyz  = (const float*)d_in[2];
    const float* qtot = (const float*)d_in[3];
    const float* w    = (const float*)d_in[4];
    const float* ztab = (const float*)d_in[5];
    float* out = (float*)d_out;            // out[0]=energy, out[1..N]=q

    // ws: [0,8192) ctr1 padded | [8192] ctr2 | [8448, +1536) qpart[384]
    //     [10240, +4800) eblk[1200] | [16384, +98304) xqp[N] float4
    char* wsb = (char*)d_ws;
    unsigned int* ctr1  = (unsigned int*)(wsb + 0);
    unsigned int* ctr2  = (unsigned int*)(wsb + 8192);
    float*        qpart = (float*)(wsb + 8448);
    float*        eblk  = (float*)(wsb + 10240);
    float4*       xqp   = (float4*)(wsb + 16384);

    pred_kernel<<<NPRED, 256, 0, stream>>>(f, z, w, ztab, xyz, qpart, xqp,
                                           ctr1, ctr2);
    pair_kernel<<<NREAL, 256, 0, stream>>>(xqp, qpart, qtot, out + 1, eblk,
                                           ctr1, ctr2, out);
}

// Round 19
// 81.219 us; speedup vs baseline: 1.1758x; 1.1758x over previous
//
#include <hip/hip_runtime.h>

#define KE_KCAL 332.0637f

constexpr int N_ATOMS = 6144;
constexpr int NREAL = 1200;             // triangular 256x64 tiles
constexpr int NPRED = 384;              // pred blocks (16 atoms each)

typedef float v2f __attribute__((ext_vector_type(2)));
typedef float v4f __attribute__((ext_vector_type(4)));

// ---------------- kernel A: pred + per-block sums + pack --------------------
__global__ __launch_bounds__(256) void pred_kernel(
    const float* __restrict__ f, const int* __restrict__ z,
    const float* __restrict__ w, const float* __restrict__ ztab,
    const float* __restrict__ xyz,
    float* __restrict__ qpart, float4* __restrict__ xqp)
{
    int t = threadIdx.x, b = blockIdx.x;
    int lane = t & 63, wid = t >> 6;

    int base = b * 16 + wid * 4;
    const float2* f2 = (const float2*)f;
    float2 wv = ((const float2*)w)[lane];
    float2 v0 = f2[(size_t)(base + 0) * 64 + lane];
    float2 v1 = f2[(size_t)(base + 1) * 64 + lane];
    float2 v2 = f2[(size_t)(base + 2) * 64 + lane];
    float2 v3 = f2[(size_t)(base + 3) * 64 + lane];
    float p0 = fmaf(v0.x, wv.x, v0.y * wv.y);
    float p1 = fmaf(v1.x, wv.x, v1.y * wv.y);
    float p2 = fmaf(v2.x, wv.x, v2.y * wv.y);
    float p3 = fmaf(v3.x, wv.x, v3.y * wv.y);
    #pragma unroll
    for (int off = 32; off > 0; off >>= 1) {
        p0 += __shfl_xor(p0, off, 64);
        p1 += __shfl_xor(p1, off, 64);
        p2 += __shfl_xor(p2, off, 64);
        p3 += __shfl_xor(p3, off, 64);
    }
    float ws_sum = 0.f;
    if (lane < 4) {
        int atom = base + lane;
        float pk = p0;
        pk = (lane == 1) ? p1 : pk;
        pk = (lane == 2) ? p2 : pk;
        pk = (lane == 3) ? p3 : pk;
        pk += ztab[z[atom]];
        xqp[atom] = make_float4(xyz[3*atom], xyz[3*atom+1], xyz[3*atom+2], pk);
        ws_sum = pk;
    }
    ws_sum += __shfl_xor(ws_sum, 1, 64);
    ws_sum += __shfl_xor(ws_sum, 2, 64);

    __shared__ float lred[4];
    if (lane == 0) lred[wid] = ws_sum;
    __syncthreads();
    if (t == 0) qpart[b] = lred[0] + lred[1] + lred[2] + lred[3];
}

// ---------------- packed pair term: 2 pairs per VOP3P stream ----------------
// term = rsq(x + fs(x)), x = r^2 (R15/R16-proven, absmax 3.8e-6).
// fs = h(v(u)): u = clamp((x-31.25)/50, +-1/2); cubic v; odd deg-7 h.
// Saturation outside [2.5, 7.5] A exact.
template<bool DIAG>
__device__ __forceinline__ v2f pair2(v2f jx, v2f jy, v2f jz, v2f jq,
                                     float px, float py, float pz, float qi,
                                     int k0, int jthresh)
{
    v2f dx = px - jx, dy = py - jy, dz = pz - jz;
    v2f x  = __builtin_elementwise_fma(dx, dx,
             __builtin_elementwise_fma(dy, dy, dz * dz));
    v2f qq = qi * jq;
    if (DIAG) {
        qq.x = ((k0     > jthresh) && (x.x > 0.f)) ? qq.x : 0.f;
        qq.y = ((k0 + 1 > jthresh) && (x.y > 0.f)) ? qq.y : 0.f;
    }
    v2f u = __builtin_elementwise_fma(x, (v2f)(0.02f), (v2f)(-0.625f));
    u = __builtin_elementwise_min(__builtin_elementwise_max(u, (v2f)(-0.5f)),
                                  (v2f)(0.5f));
    v2f v = __builtin_elementwise_fma(u,
              __builtin_elementwise_fma(u,
                __builtin_elementwise_fma(u, (v2f)(0.333856f),
                                          (v2f)(-0.472136f)),
                (v2f)(0.916536f)),
              (v2f)(0.118034f));
    v2f v2 = v * v;
    v2f p  = __builtin_elementwise_fma(v2,
               __builtin_elementwise_fma(v2,
                 __builtin_elementwise_fma(v2, (v2f)(-8.f), (v2f)(12.f)),
                 (v2f)(-6.5f)),
               (v2f)(2.f));
    v2f arg = __builtin_elementwise_fma(-v, p, x + 0.5f);   // x + fs
    v2f rs;
    rs.x = __builtin_amdgcn_rsqf(arg.x);
    rs.y = __builtin_amdgcn_rsqf(arg.y);
    return qq * rs;
}

// ---------------- kernel B: pair energy, packed-math loop -------------------
// 1200 triangular blocks x 256 thr (R12/R15 proven skeleton). j-tile staged
// SoA in LDS so v4f loads give packed pairs in adjacent VGPRs. Software-
// pipelined (prefetch 4 j's, 2 packed accumulator chains).
__global__ __launch_bounds__(256) void pair_kernel(
    const float4* __restrict__ xqp, const float* __restrict__ qpart,
    const float* __restrict__ total_charge,
    float* __restrict__ qout, float* __restrict__ eblk)
{
    int t = threadIdx.x, b = blockIdx.x;
    int lane = t & 63, wid = t >> 6;
    __shared__ float lred[4];
    __shared__ __align__(16) float sx[64], sy[64], sz[64], sq[64];

    // charge correction from the 384 per-block partials
    float s = qpart[t];
    if (t < NPRED - 256) s += qpart[256 + t];
    #pragma unroll
    for (int off = 32; off > 0; off >>= 1)
        s += __shfl_xor(s, off, 64);
    if (lane == 0) lred[wid] = s;
    __syncthreads();
    float S = lred[0] + lred[1] + lred[2] + lred[3];
    float corr = (total_charge[0] - S) * (1.0f / (float)N_ATOMS);

    // decode triangular (bi, bj): bj in [4*bi, 96)
    int bi = 0, off = 0;
    while (b >= off + (96 - 4 * bi)) { off += 96 - 4 * bi; ++bi; }
    int bj = 4 * bi + (b - off);

    int gj0 = bj * 64;
    if (t < 64) {
        float4 a = xqp[gj0 + t];
        sx[t] = a.x; sy[t] = a.y; sz[t] = a.z; sq[t] = a.w + corr;
    }
    int gi = bi * 256 + t;
    float4 pi = xqp[gi];
    float qi = pi.w + corr;
    if (bj == 4 * bi) qout[gi] = qi;
    __syncthreads();

    int jthresh = gi - gj0;             // pair valid iff k > jthresh
    bool diag = (bj - 4 * bi) < 4;      // i/j ranges overlap (wave-uniform)

    v2f accA = {0.f, 0.f}, accB = {0.f, 0.f};

#define PAIR_LOOP(DIAG_FLAG)                                                  \
    {                                                                         \
        v4f cx = *(const v4f*)&sx[0], cy = *(const v4f*)&sy[0];               \
        v4f cz = *(const v4f*)&sz[0], cq = *(const v4f*)&sq[0];               \
        _Pragma("unroll")                                                     \
        for (int k = 0; k < 64; k += 4) {                                     \
            v4f nx, ny, nz, nq;                                               \
            if (k + 4 < 64) {                                                 \
                nx = *(const v4f*)&sx[k+4]; ny = *(const v4f*)&sy[k+4];       \
                nz = *(const v4f*)&sz[k+4]; nq = *(const v4f*)&sq[k+4];       \
            }                                                                 \
            accA += pair2<DIAG_FLAG>(cx.lo, cy.lo, cz.lo, cq.lo,              \
                                     pi.x, pi.y, pi.z, qi, k,     jthresh);   \
            accB += pair2<DIAG_FLAG>(cx.hi, cy.hi, cz.hi, cq.hi,              \
                                     pi.x, pi.y, pi.z, qi, k + 2, jthresh);   \
            cx = nx; cy = ny; cz = nz; cq = nq;                               \
        }                                                                     \
    }

    if (diag) PAIR_LOOP(true) else PAIR_LOOP(false)
#undef PAIR_LOOP

    float acc = (accA.x + accA.y) + (accB.x + accB.y);

    #pragma unroll
    for (int o2 = 32; o2 > 0; o2 >>= 1)
        acc += __shfl_down(acc, o2, 64);
    __syncthreads();                    // lred reuse
    if (lane == 0) lred[wid] = acc;
    __syncthreads();
    if (t == 0) eblk[b] = lred[0] + lred[1] + lred[2] + lred[3];
}

// ---------------- kernel C: finalize energy ---------------------------------
__global__ __launch_bounds__(256) void efin_kernel(
    const float* __restrict__ eblk, float* __restrict__ out0)
{
    int t = threadIdx.x;
    float e = 0.f;
    for (int k = t; k < NREAL; k += 256) e += eblk[k];
    #pragma unroll
    for (int o2 = 32; o2 > 0; o2 >>= 1)
        e += __shfl_down(e, o2, 64);
    __shared__ float wacc[4];
    if ((t & 63) == 0) wacc[t >> 6] = e;
    __syncthreads();
    if (t == 0) out0[0] = KE_KCAL * (wacc[0] + wacc[1] + wacc[2] + wacc[3]);
}

extern "C" void kernel_launch(void* const* d_in, const int* in_sizes, int n_in,
                              void* d_out, int out_size, void* d_ws, size_t ws_size,
                              hipStream_t stream) {
    const float* f    = (const float*)d_in[0];
    const int*   z    = (const int*)  d_in[1];
    const float* xyz  = (const float*)d_in[2];
    const float* qtot = (const float*)d_in[3];
    const float* w    = (const float*)d_in[4];
    const float* ztab = (const float*)d_in[5];
    float* out = (float*)d_out;            // out[0]=energy, out[1..N]=q

    // ws: [0, 1536) qpart[384] | [2048, 2048+4800) eblk[1200]
    //     [16384, +98304) xqp[N] float4   (no zeroing needed anywhere)
    char* wsb = (char*)d_ws;
    float*  qpart = (float*)(wsb + 0);
    float*  eblk  = (float*)(wsb + 2048);
    float4* xqp   = (float4*)(wsb + 16384);

    pred_kernel<<<NPRED, 256, 0, stream>>>(f, z, w, ztab, xyz, qpart, xqp);
    pair_kernel<<<NREAL, 256, 0, stream>>>(xqp, qpart, qtot, out + 1, eblk);
    efin_kernel<<<1, 256, 0, stream>>>(eblk, out);
}